// Round 5
// baseline (1676.582 us; speedup 1.0000x reference)
//
#include <hip/hip_runtime.h>
#include <math.h>

// ---------------------------------------------------------------------------
// GAT pipeline: 3x (GEMM+alpha fused -> CSR segment-softmax aggregate) + FC
// R5: GEMM back to RB=4 (44 VGPR), 512-thread blocks (8 waves) -> 4 blocks/CU
//     = 32 waves/CU ceiling (R4's RB=8/256-thr gave occ 30%, VALUBusy 28%).
// ---------------------------------------------------------------------------

// pass 1: cnt[dst]++ (atomic), remember each edge's arrival rank.
__global__ void count_rank_kernel(const int* __restrict__ ei, int E, int N,
                                  int* __restrict__ cnt, int* __restrict__ rank) {
    const int Etot = E + N;
    const int T = gridDim.x * blockDim.x;
    int e = blockIdx.x * blockDim.x + threadIdx.x;
#pragma unroll 4
    for (int u = 0; u < 4; ++u, e += T) {
        if (e < Etot) {
            int dst = (e < E) ? ei[E + e] : (e - E);   // self-loops appended
            rank[e] = atomicAdd(&cnt[dst], 1);
        }
    }
}

__global__ __launch_bounds__(1024) void scan_kernel(const int* __restrict__ cnt,
                                                    int N, int Etot,
                                                    int* __restrict__ row_ptr) {
    __shared__ int sums[1024];
    int tid = threadIdx.x;
    int chunk = (N + 1023) >> 10;
    int lo = tid * chunk;
    int hi = lo + chunk; if (hi > N) hi = N; if (lo > N) lo = N;
    int s = 0;
    for (int i = lo; i < hi; ++i) s += cnt[i];
    sums[tid] = s;
    __syncthreads();
    for (int off = 1; off < 1024; off <<= 1) {
        int t = (tid >= off) ? sums[tid - off] : 0;
        __syncthreads();
        sums[tid] += t;
        __syncthreads();
    }
    int run = sums[tid] - s;   // exclusive base for this thread's chunk
    for (int i = lo; i < hi; ++i) {
        row_ptr[i] = run;
        run += cnt[i];
    }
    if (tid == 0) row_ptr[N] = Etot;
}

// pass 3: pos = row_ptr[dst] + rank[e]; atomic-free scattered store.
__global__ void scatter_kernel(const int* __restrict__ ei, int E, int N,
                               const int* __restrict__ row_ptr,
                               const int* __restrict__ rank,
                               int* __restrict__ csr_src) {
    const int Etot = E + N;
    const int T = gridDim.x * blockDim.x;
    int e = blockIdx.x * blockDim.x + threadIdx.x;
#pragma unroll 4
    for (int u = 0; u < 4; ++u, e += T) {
        if (e < Etot) {
            int src, dst;
            if (e < E) { src = ei[e]; dst = ei[E + e]; }
            else       { src = e - E; dst = e - E; }
            csr_src[row_ptr[dst] + rank[e]] = src;
        }
    }
}

// ---------------------------------------------------------------------------
// GEMM: out[n, cb+m] = sum_k in[n,k]*W[k,cb+m].  512-thread blocks (8 waves),
// W chunk staged to LDS once (b128 conflict-free), grid-stride over row
// groups of RB=4 rows/wave. LDS layout wlds4[k4][c] = 4 consecutive k values.
// ALPHA: fused alpha_s/alpha_d via wave shfl reduction over the output row:
//   0=none  1=(H2,C32,PL1: segmented 32-lane)  2=(H2,C64,PL2)  3=(H1,C64,PL1)
// K*CHUNK <= 8192 (32 KB LDS) -> 4 blocks/CU (thread-capped), 32 waves/CU.
// ---------------------------------------------------------------------------
template <int K, int CHUNK, int RB, int ALPHA, int MINW>
__global__ __launch_bounds__(512, MINW) void gemm_kernel(
        const float* __restrict__ in,
        const float* __restrict__ W,
        const float* __restrict__ bias,
        float* __restrict__ out,
        const float* __restrict__ a_src,
        const float* __restrict__ a_dst,
        float* __restrict__ alpS,
        float* __restrict__ alpD,
        int N, int M, int relu) {
    constexpr int PL = CHUNK / 64;
    constexpr int K4 = K / 4;
    __shared__ float wlds[K * CHUNK];
    const int cb = blockIdx.y * CHUNK;
    for (int idx = threadIdx.x; idx < K4 * CHUNK; idx += 512) {
        int k4 = idx / CHUNK, c = idx % CHUNK;
        const float* wp = W + (size_t)(4 * k4) * M + cb + c;
        float4 v;
        v.x = wp[0];
        v.y = wp[(size_t)M];
        v.z = wp[(size_t)2 * M];
        v.w = wp[(size_t)3 * M];
        ((float4*)wlds)[idx] = v;
    }
    __syncthreads();

    const int wid  = threadIdx.x >> 6;   // 0..7
    const int lane = threadIdx.x & 63;
    const float4* wlds4 = (const float4*)wlds;

    float b[PL], aSv[PL], aDv[PL];
#pragma unroll
    for (int j = 0; j < PL; ++j) {
        b[j] = bias ? bias[cb + lane + 64 * j] : 0.0f;
        if (ALPHA) { aSv[j] = a_src[lane + 64 * j]; aDv[j] = a_dst[lane + 64 * j]; }
    }

    const int groups = (N + RB - 1) / RB;
    for (int g = blockIdx.x * 8 + wid; g < groups; g += gridDim.x * 8) {
        const int n0 = g * RB;
        const bool full = (n0 + RB <= N);

        float acc[RB][PL];
#pragma unroll
        for (int r = 0; r < RB; ++r)
#pragma unroll
            for (int j = 0; j < PL; ++j) acc[r][j] = 0.0f;

        const float* xr = in + (size_t)n0 * K;

#pragma unroll 2
        for (int k4 = 0; k4 < K4; ++k4) {
            float4 xv[RB];
#pragma unroll
            for (int r = 0; r < RB; ++r) {
                if (full || n0 + r < N)
                    xv[r] = ((const float4*)(xr + (size_t)r * K))[k4];
                else
                    xv[r] = make_float4(0.f, 0.f, 0.f, 0.f);
            }
#pragma unroll
            for (int j = 0; j < PL; ++j) {
                float4 wv = wlds4[k4 * CHUNK + lane + 64 * j];
#pragma unroll
                for (int r = 0; r < RB; ++r) {
                    acc[r][j] += xv[r].x * wv.x;
                    acc[r][j] += xv[r].y * wv.y;
                    acc[r][j] += xv[r].z * wv.z;
                    acc[r][j] += xv[r].w * wv.w;
                }
            }
        }

#pragma unroll
        for (int r = 0; r < RB; ++r) {
            if (!full && n0 + r >= N) break;
            const int n = n0 + r;
            float v[PL];
#pragma unroll
            for (int j = 0; j < PL; ++j) {
                v[j] = acc[r][j] + b[j];
                if (relu) v[j] = fmaxf(v[j], 0.0f);
                out[(size_t)n * M + cb + lane + 64 * j] = v[j];
            }
            if (ALPHA) {
                float ps[PL], pd[PL];
#pragma unroll
                for (int j = 0; j < PL; ++j) { ps[j] = v[j] * aSv[j]; pd[j] = v[j] * aDv[j]; }
                const int m0 = (ALPHA == 1) ? 16 : 32;   // 32-lane segmented vs full wave
                for (int m = m0; m >= 1; m >>= 1) {
#pragma unroll
                    for (int j = 0; j < PL; ++j) {
                        ps[j] += __shfl_xor(ps[j], m, 64);
                        pd[j] += __shfl_xor(pd[j], m, 64);
                    }
                }
                if (ALPHA == 1) {
                    if ((lane & 31) == 0) {
                        int idx = n * 2 + (lane >> 5);
                        alpS[idx] = ps[0]; alpD[idx] = pd[0];
                    }
                } else if (ALPHA == 2) {
                    if (lane == 0) {
#pragma unroll
                        for (int j = 0; j < PL; ++j) {
                            alpS[n * 2 + j] = ps[j]; alpD[n * 2 + j] = pd[j];
                        }
                    }
                } else {
                    if (lane == 0) { alpS[n] = ps[0]; alpD[n] = pd[0]; }
                }
            }
        }
    }
}

// ---------------------------------------------------------------------------
// Aggregate: one wave per dst node, single pass, online softmax, 8-edge unroll.
// PL==1: lane -> (head=lane/C, c=lane%C)  [needs H*C==64]
// PL==2: lane covers (head=j, c=lane), j=0,1 [needs C==64,H==2]
// ---------------------------------------------------------------------------
template <int H, int C, int PL>
__global__ __launch_bounds__(256) void aggregate_kernel(
        const float* __restrict__ h,
        const float* __restrict__ alpha_s,
        const float* __restrict__ alpha_d,
        const int* __restrict__ row_ptr,
        const int* __restrict__ csr_src,
        const float* __restrict__ bias,
        float* __restrict__ out, int N) {
    constexpr int M = H * C;
    constexpr int U = 8;
    const int wid  = threadIdx.x >> 6;
    const int lane = threadIdx.x & 63;
    const int n = blockIdx.x * 4 + wid;
    if (n >= N) return;

    const int lo = row_ptr[n], hi = row_ptr[n + 1];

    int head[PL], col[PL];
    float adv[PL], mx[PL], den[PL], acc[PL];
#pragma unroll
    for (int j = 0; j < PL; ++j) {
        head[j] = (PL == 1) ? (lane / C) : j;
        col[j]  = (PL == 1) ? lane : (j * C + lane);
        adv[j]  = alpha_d[n * H + head[j]];
        mx[j]   = -INFINITY;
        den[j]  = 0.0f;
        acc[j]  = 0.0f;
    }

    int e = lo;
    for (; e + U <= hi; e += U) {
        int s[U];
#pragma unroll
        for (int u = 0; u < U; ++u) s[u] = csr_src[e + u];
        float ev[U][PL], hv[U][PL];
#pragma unroll
        for (int u = 0; u < U; ++u)
#pragma unroll
            for (int j = 0; j < PL; ++j)
                ev[u][j] = alpha_s[s[u] * H + head[j]];
#pragma unroll
        for (int u = 0; u < U; ++u)
#pragma unroll
            for (int j = 0; j < PL; ++j)
                hv[u][j] = h[(size_t)s[u] * M + col[j]];
#pragma unroll
        for (int u = 0; u < U; ++u)
#pragma unroll
            for (int j = 0; j < PL; ++j) {
                float evv = ev[u][j] + adv[j];
                evv = evv > 0.0f ? evv : 0.2f * evv;
                float mnew = fmaxf(mx[j], evv);
                float sc = __expf(mx[j] - mnew);   // first edge: exp(-inf)=0
                float p  = __expf(evv - mnew);
                den[j] = den[j] * sc + p;
                acc[j] = acc[j] * sc + p * hv[u][j];
                mx[j]  = mnew;
            }
    }
    for (; e < hi; ++e) {
        int s = csr_src[e];
#pragma unroll
        for (int j = 0; j < PL; ++j) {
            float evv = alpha_s[s * H + head[j]] + adv[j];
            evv = evv > 0.0f ? evv : 0.2f * evv;
            float mnew = fmaxf(mx[j], evv);
            float sc = __expf(mx[j] - mnew);
            float p  = __expf(evv - mnew);
            den[j] = den[j] * sc + p;
            acc[j] = acc[j] * sc + p * h[(size_t)s * M + col[j]];
            mx[j]  = mnew;
        }
    }

#pragma unroll
    for (int j = 0; j < PL; ++j) {
        float v = acc[j] / den[j] + bias[col[j]];
        out[(size_t)n * M + col[j]] = fmaxf(v, 0.0f);
    }
}

// ---------------------------------------------------------------------------

extern "C" void kernel_launch(void* const* d_in, const int* in_sizes, int n_in,
                              void* d_out, int out_size, void* d_ws, size_t ws_size,
                              hipStream_t stream) {
    const float* x   = (const float*)d_in[0];
    const int*   ei  = (const int*)  d_in[1];
    const float* w1  = (const float*)d_in[2];
    const float* as1 = (const float*)d_in[3];
    const float* ad1 = (const float*)d_in[4];
    const float* b1  = (const float*)d_in[5];
    const float* w2  = (const float*)d_in[6];
    const float* as2 = (const float*)d_in[7];
    const float* ad2 = (const float*)d_in[8];
    const float* b2  = (const float*)d_in[9];
    const float* w3  = (const float*)d_in[10];
    const float* as3 = (const float*)d_in[11];
    const float* ad3 = (const float*)d_in[12];
    const float* b3  = (const float*)d_in[13];
    const float* fcw = (const float*)d_in[14];
    const float* fcb = (const float*)d_in[15];
    float* out = (float*)d_out;

    const int N = in_sizes[0] / 128;
    const int E = in_sizes[1] / 2;
    const int Etot = E + N;

    // workspace carve-up (256B aligned regions)
    char* p = (char*)d_ws;
    auto alloc = [&](size_t bytes) {
        char* r = p;
        p += (bytes + 255) & ~(size_t)255;
        return r;
    };
    int*   cnt     = (int*)  alloc((size_t)N * 4);
    int*   row_ptr = (int*)  alloc((size_t)(N + 1) * 4);
    int*   rank    = (int*)  alloc((size_t)Etot * 4);
    int*   csr_src = (int*)  alloc((size_t)Etot * 4);
    float* bufA    = (float*)alloc((size_t)N * 128 * 4);
    float* bufB    = (float*)alloc((size_t)N * 128 * 4);
    float* alpS    = (float*)alloc((size_t)N * 2 * 4);
    float* alpD    = (float*)alloc((size_t)N * 2 * 4);
    (void)ws_size; (void)n_in; (void)out_size;

    // ---- build CSR by dst (atomics only in pass 1) ----
    hipMemsetAsync(cnt, 0, (size_t)N * 4, stream);
    int eb4 = (Etot / 4 + 255) / 256 + 1;   // 4 edges/thread
    count_rank_kernel<<<eb4, 256, 0, stream>>>(ei, E, N, cnt, rank);
    scan_kernel<<<1, 1024, 0, stream>>>(cnt, N, Etot, row_ptr);
    scatter_kernel<<<eb4, 256, 0, stream>>>(ei, E, N, row_ptr, rank, csr_src);

    int gb = (N + 3) / 4;         // aggregate: 4 waves/block, 1 node/wave
    const int GB = 1024;          // gemm blocks: 4/CU at 32 KB LDS, 512 thr

    // ---- layer 1: 128 -> H2 x C32, concat ----
    gemm_kernel<128, 64, 4, 1, 6><<<dim3(GB, 1), 512, 0, stream>>>(
        x, w1, nullptr, bufA, as1, ad1, alpS, alpD, N, 64, 0);
    aggregate_kernel<2, 32, 1><<<gb, 256, 0, stream>>>(bufA, alpS, alpD, row_ptr, csr_src, b1, bufB, N);

    // ---- layer 2: 64 -> H2 x C64, concat ----
    gemm_kernel<64, 128, 4, 2, 6><<<dim3(GB, 1), 512, 0, stream>>>(
        bufB, w2, nullptr, bufA, as2, ad2, alpS, alpD, N, 128, 0);
    aggregate_kernel<2, 64, 2><<<gb, 256, 0, stream>>>(bufA, alpS, alpD, row_ptr, csr_src, b2, bufB, N);

    // ---- layer 3: 128 -> H1 x C64, mean (=identity for 1 head) ----
    gemm_kernel<128, 64, 4, 3, 6><<<dim3(GB, 1), 512, 0, stream>>>(
        bufB, w3, nullptr, bufA, as3, ad3, alpS, alpD, N, 64, 0);
    aggregate_kernel<1, 64, 1><<<gb, 256, 0, stream>>>(bufA, alpS, alpD, row_ptr, csr_src, b3, bufB, N);

    // ---- FC: 64 -> 512 + relu ----
    gemm_kernel<64, 128, 4, 0, 8><<<dim3(GB / 4, 4), 512, 0, stream>>>(
        bufB, fcw, fcb, out, nullptr, nullptr, nullptr, nullptr, N, 512, 1);
}

// Round 6
// 957.748 us; speedup vs baseline: 1.7505x; 1.7505x over previous
//
#include <hip/hip_runtime.h>
#include <math.h>

// ---------------------------------------------------------------------------
// GAT pipeline: 3x (GEMM+alpha fused -> CSR segment-softmax aggregate) + FC
// R6: GEMM reverted to 256-thr/RB=4 (R5's __launch_bounds__(512,8) forced
//     VGPR=32 -> 2 GB spill traffic). x row base made wave-uniform via
//     readfirstlane so x loads go down the scalar (SMEM) path.
// ---------------------------------------------------------------------------

// pass 1: cnt[dst]++ (atomic), remember each edge's arrival rank.
__global__ void count_rank_kernel(const int* __restrict__ ei, int E, int N,
                                  int* __restrict__ cnt, int* __restrict__ rank) {
    const int Etot = E + N;
    const int T = gridDim.x * blockDim.x;
    int e = blockIdx.x * blockDim.x + threadIdx.x;
#pragma unroll 4
    for (int u = 0; u < 4; ++u, e += T) {
        if (e < Etot) {
            int dst = (e < E) ? ei[E + e] : (e - E);   // self-loops appended
            rank[e] = atomicAdd(&cnt[dst], 1);
        }
    }
}

__global__ __launch_bounds__(1024) void scan_kernel(const int* __restrict__ cnt,
                                                    int N, int Etot,
                                                    int* __restrict__ row_ptr) {
    __shared__ int sums[1024];
    int tid = threadIdx.x;
    int chunk = (N + 1023) >> 10;
    int lo = tid * chunk;
    int hi = lo + chunk; if (hi > N) hi = N; if (lo > N) lo = N;
    int s = 0;
    for (int i = lo; i < hi; ++i) s += cnt[i];
    sums[tid] = s;
    __syncthreads();
    for (int off = 1; off < 1024; off <<= 1) {
        int t = (tid >= off) ? sums[tid - off] : 0;
        __syncthreads();
        sums[tid] += t;
        __syncthreads();
    }
    int run = sums[tid] - s;   // exclusive base for this thread's chunk
    for (int i = lo; i < hi; ++i) {
        row_ptr[i] = run;
        run += cnt[i];
    }
    if (tid == 0) row_ptr[N] = Etot;
}

// pass 3: pos = row_ptr[dst] + rank[e]; atomic-free scattered store.
__global__ void scatter_kernel(const int* __restrict__ ei, int E, int N,
                               const int* __restrict__ row_ptr,
                               const int* __restrict__ rank,
                               int* __restrict__ csr_src) {
    const int Etot = E + N;
    const int T = gridDim.x * blockDim.x;
    int e = blockIdx.x * blockDim.x + threadIdx.x;
#pragma unroll 4
    for (int u = 0; u < 4; ++u, e += T) {
        if (e < Etot) {
            int src, dst;
            if (e < E) { src = ei[e]; dst = ei[E + e]; }
            else       { src = e - E; dst = e - E; }
            csr_src[row_ptr[dst] + rank[e]] = src;
        }
    }
}

// ---------------------------------------------------------------------------
// GEMM: out[n, cb+m] = sum_k in[n,k]*W[k,cb+m].  256-thread blocks (4 waves),
// W chunk staged to LDS once (b128 conflict-free), grid-stride over row
// groups of RB=4 rows/wave. Row base is wave-uniform (readfirstlane) so x
// loads use the scalar path; W from LDS; inner loop is FMA-dominated.
// ALPHA: fused alpha_s/alpha_d via wave shfl reduction over the output row:
//   0=none  1=(H2,C32,PL1: segmented 32-lane)  2=(H2,C64,PL2)  3=(H1,C64,PL1)
// K*CHUNK <= 8192 (32 KB LDS).
// ---------------------------------------------------------------------------
template <int K, int CHUNK, int RB, int ALPHA>
__global__ __launch_bounds__(256) void gemm_kernel(
        const float* __restrict__ in,
        const float* __restrict__ W,
        const float* __restrict__ bias,
        float* __restrict__ out,
        const float* __restrict__ a_src,
        const float* __restrict__ a_dst,
        float* __restrict__ alpS,
        float* __restrict__ alpD,
        int N, int M, int relu) {
    constexpr int PL = CHUNK / 64;
    constexpr int K4 = K / 4;
    __shared__ float wlds[K * CHUNK];
    const int cb = blockIdx.y * CHUNK;
    for (int idx = threadIdx.x; idx < K4 * CHUNK; idx += 256) {
        int k4 = idx / CHUNK, c = idx % CHUNK;
        const float* wp = W + (size_t)(4 * k4) * M + cb + c;
        float4 v;
        v.x = wp[0];
        v.y = wp[(size_t)M];
        v.z = wp[(size_t)2 * M];
        v.w = wp[(size_t)3 * M];
        ((float4*)wlds)[idx] = v;
    }
    __syncthreads();

    // wave-uniform wave id -> row addresses provably uniform -> scalar loads
    const int wid  = __builtin_amdgcn_readfirstlane(threadIdx.x >> 6);
    const int lane = threadIdx.x & 63;
    const float4* wlds4 = (const float4*)wlds;

    float b[PL], aSv[PL], aDv[PL];
#pragma unroll
    for (int j = 0; j < PL; ++j) {
        b[j] = bias ? bias[cb + lane + 64 * j] : 0.0f;
        if (ALPHA) { aSv[j] = a_src[lane + 64 * j]; aDv[j] = a_dst[lane + 64 * j]; }
    }

    const int groups = (N + RB - 1) / RB;
    for (int g = blockIdx.x * 4 + wid; g < groups; g += gridDim.x * 4) {
        const int n0 = g * RB;
        const bool full = (n0 + RB <= N);

        float acc[RB][PL];
#pragma unroll
        for (int r = 0; r < RB; ++r)
#pragma unroll
            for (int j = 0; j < PL; ++j) acc[r][j] = 0.0f;

        const float4* xp = (const float4*)(in + (size_t)n0 * K);

#pragma unroll 2
        for (int k4 = 0; k4 < K4; ++k4) {
            float4 xv[RB];
#pragma unroll
            for (int r = 0; r < RB; ++r) {
                if (full || n0 + r < N)
                    xv[r] = xp[(size_t)r * (K / 4) + k4];   // uniform -> s_load
                else
                    xv[r] = make_float4(0.f, 0.f, 0.f, 0.f);
            }
#pragma unroll
            for (int j = 0; j < PL; ++j) {
                float4 wv = wlds4[k4 * CHUNK + lane + 64 * j];
#pragma unroll
                for (int r = 0; r < RB; ++r) {
                    acc[r][j] += xv[r].x * wv.x;
                    acc[r][j] += xv[r].y * wv.y;
                    acc[r][j] += xv[r].z * wv.z;
                    acc[r][j] += xv[r].w * wv.w;
                }
            }
        }

#pragma unroll
        for (int r = 0; r < RB; ++r) {
            if (!full && n0 + r >= N) break;
            const int n = n0 + r;
            float v[PL];
#pragma unroll
            for (int j = 0; j < PL; ++j) {
                v[j] = acc[r][j] + b[j];
                if (relu) v[j] = fmaxf(v[j], 0.0f);
                out[(size_t)n * M + cb + lane + 64 * j] = v[j];
            }
            if (ALPHA) {
                float ps[PL], pd[PL];
#pragma unroll
                for (int j = 0; j < PL; ++j) { ps[j] = v[j] * aSv[j]; pd[j] = v[j] * aDv[j]; }
                const int m0 = (ALPHA == 1) ? 16 : 32;   // 32-lane segmented vs full wave
                for (int m = m0; m >= 1; m >>= 1) {
#pragma unroll
                    for (int j = 0; j < PL; ++j) {
                        ps[j] += __shfl_xor(ps[j], m, 64);
                        pd[j] += __shfl_xor(pd[j], m, 64);
                    }
                }
                if (ALPHA == 1) {
                    if ((lane & 31) == 0) {
                        int idx = n * 2 + (lane >> 5);
                        alpS[idx] = ps[0]; alpD[idx] = pd[0];
                    }
                } else if (ALPHA == 2) {
                    if (lane == 0) {
#pragma unroll
                        for (int j = 0; j < PL; ++j) {
                            alpS[n * 2 + j] = ps[j]; alpD[n * 2 + j] = pd[j];
                        }
                    }
                } else {
                    if (lane == 0) { alpS[n] = ps[0]; alpD[n] = pd[0]; }
                }
            }
        }
    }
}

// ---------------------------------------------------------------------------
// Aggregate: one wave per dst node, single pass, online softmax, 8-edge unroll.
// PL==1: lane -> (head=lane/C, c=lane%C)  [needs H*C==64]
// PL==2: lane covers (head=j, c=lane), j=0,1 [needs C==64,H==2]
// ---------------------------------------------------------------------------
template <int H, int C, int PL>
__global__ __launch_bounds__(256) void aggregate_kernel(
        const float* __restrict__ h,
        const float* __restrict__ alpha_s,
        const float* __restrict__ alpha_d,
        const int* __restrict__ row_ptr,
        const int* __restrict__ csr_src,
        const float* __restrict__ bias,
        float* __restrict__ out, int N) {
    constexpr int M = H * C;
    constexpr int U = 8;
    const int wid  = threadIdx.x >> 6;
    const int lane = threadIdx.x & 63;
    const int n = blockIdx.x * 4 + wid;
    if (n >= N) return;

    const int lo = row_ptr[n], hi = row_ptr[n + 1];

    int head[PL], col[PL];
    float adv[PL], mx[PL], den[PL], acc[PL];
#pragma unroll
    for (int j = 0; j < PL; ++j) {
        head[j] = (PL == 1) ? (lane / C) : j;
        col[j]  = (PL == 1) ? lane : (j * C + lane);
        adv[j]  = alpha_d[n * H + head[j]];
        mx[j]   = -INFINITY;
        den[j]  = 0.0f;
        acc[j]  = 0.0f;
    }

    int e = lo;
    for (; e + U <= hi; e += U) {
        int s[U];
#pragma unroll
        for (int u = 0; u < U; ++u) s[u] = csr_src[e + u];
        float ev[U][PL], hv[U][PL];
#pragma unroll
        for (int u = 0; u < U; ++u)
#pragma unroll
            for (int j = 0; j < PL; ++j)
                ev[u][j] = alpha_s[s[u] * H + head[j]];
#pragma unroll
        for (int u = 0; u < U; ++u)
#pragma unroll
            for (int j = 0; j < PL; ++j)
                hv[u][j] = h[(size_t)s[u] * M + col[j]];
#pragma unroll
        for (int u = 0; u < U; ++u)
#pragma unroll
            for (int j = 0; j < PL; ++j) {
                float evv = ev[u][j] + adv[j];
                evv = evv > 0.0f ? evv : 0.2f * evv;
                float mnew = fmaxf(mx[j], evv);
                float sc = __expf(mx[j] - mnew);   // first edge: exp(-inf)=0
                float p  = __expf(evv - mnew);
                den[j] = den[j] * sc + p;
                acc[j] = acc[j] * sc + p * hv[u][j];
                mx[j]  = mnew;
            }
    }
    for (; e < hi; ++e) {
        int s = csr_src[e];
#pragma unroll
        for (int j = 0; j < PL; ++j) {
            float evv = alpha_s[s * H + head[j]] + adv[j];
            evv = evv > 0.0f ? evv : 0.2f * evv;
            float mnew = fmaxf(mx[j], evv);
            float sc = __expf(mx[j] - mnew);
            float p  = __expf(evv - mnew);
            den[j] = den[j] * sc + p;
            acc[j] = acc[j] * sc + p * h[(size_t)s * M + col[j]];
            mx[j]  = mnew;
        }
    }

#pragma unroll
    for (int j = 0; j < PL; ++j) {
        float v = acc[j] / den[j] + bias[col[j]];
        out[(size_t)n * M + col[j]] = fmaxf(v, 0.0f);
    }
}

// ---------------------------------------------------------------------------

extern "C" void kernel_launch(void* const* d_in, const int* in_sizes, int n_in,
                              void* d_out, int out_size, void* d_ws, size_t ws_size,
                              hipStream_t stream) {
    const float* x   = (const float*)d_in[0];
    const int*   ei  = (const int*)  d_in[1];
    const float* w1  = (const float*)d_in[2];
    const float* as1 = (const float*)d_in[3];
    const float* ad1 = (const float*)d_in[4];
    const float* b1  = (const float*)d_in[5];
    const float* w2  = (const float*)d_in[6];
    const float* as2 = (const float*)d_in[7];
    const float* ad2 = (const float*)d_in[8];
    const float* b2  = (const float*)d_in[9];
    const float* w3  = (const float*)d_in[10];
    const float* as3 = (const float*)d_in[11];
    const float* ad3 = (const float*)d_in[12];
    const float* b3  = (const float*)d_in[13];
    const float* fcw = (const float*)d_in[14];
    const float* fcb = (const float*)d_in[15];
    float* out = (float*)d_out;

    const int N = in_sizes[0] / 128;
    const int E = in_sizes[1] / 2;
    const int Etot = E + N;

    // workspace carve-up (256B aligned regions)
    char* p = (char*)d_ws;
    auto alloc = [&](size_t bytes) {
        char* r = p;
        p += (bytes + 255) & ~(size_t)255;
        return r;
    };
    int*   cnt     = (int*)  alloc((size_t)N * 4);
    int*   row_ptr = (int*)  alloc((size_t)(N + 1) * 4);
    int*   rank    = (int*)  alloc((size_t)Etot * 4);
    int*   csr_src = (int*)  alloc((size_t)Etot * 4);
    float* bufA    = (float*)alloc((size_t)N * 128 * 4);
    float* bufB    = (float*)alloc((size_t)N * 128 * 4);
    float* alpS    = (float*)alloc((size_t)N * 2 * 4);
    float* alpD    = (float*)alloc((size_t)N * 2 * 4);
    (void)ws_size; (void)n_in; (void)out_size;

    // ---- build CSR by dst (atomics only in pass 1) ----
    hipMemsetAsync(cnt, 0, (size_t)N * 4, stream);
    int eb4 = (Etot / 4 + 255) / 256 + 1;   // 4 edges/thread
    count_rank_kernel<<<eb4, 256, 0, stream>>>(ei, E, N, cnt, rank);
    scan_kernel<<<1, 1024, 0, stream>>>(cnt, N, Etot, row_ptr);
    scatter_kernel<<<eb4, 256, 0, stream>>>(ei, E, N, row_ptr, rank, csr_src);

    int gb = (N + 3) / 4;         // aggregate: 4 waves/block, 1 node/wave
    const int GB = 1024;          // gemm persistent blocks

    // ---- layer 1: 128 -> H2 x C32, concat ----
    gemm_kernel<128, 64, 4, 1><<<dim3(GB, 1), 256, 0, stream>>>(
        x, w1, nullptr, bufA, as1, ad1, alpS, alpD, N, 64, 0);
    aggregate_kernel<2, 32, 1><<<gb, 256, 0, stream>>>(bufA, alpS, alpD, row_ptr, csr_src, b1, bufB, N);

    // ---- layer 2: 64 -> H2 x C64, concat ----
    gemm_kernel<64, 128, 4, 2><<<dim3(GB, 1), 256, 0, stream>>>(
        bufB, w2, nullptr, bufA, as2, ad2, alpS, alpD, N, 128, 0);
    aggregate_kernel<2, 64, 2><<<gb, 256, 0, stream>>>(bufA, alpS, alpD, row_ptr, csr_src, b2, bufB, N);

    // ---- layer 3: 128 -> H1 x C64, mean (=identity for 1 head) ----
    gemm_kernel<128, 64, 4, 3><<<dim3(GB, 1), 256, 0, stream>>>(
        bufB, w3, nullptr, bufA, as3, ad3, alpS, alpD, N, 64, 0);
    aggregate_kernel<1, 64, 1><<<gb, 256, 0, stream>>>(bufA, alpS, alpD, row_ptr, csr_src, b3, bufB, N);

    // ---- FC: 64 -> 512 + relu ----
    gemm_kernel<64, 128, 4, 0><<<dim3(GB / 4, 4), 256, 0, stream>>>(
        bufB, fcw, fcb, out, nullptr, nullptr, nullptr, nullptr, N, 512, 1);
}

// Round 7
// 910.606 us; speedup vs baseline: 1.8412x; 1.0518x over previous
//
#include <hip/hip_runtime.h>
#include <math.h>

// ---------------------------------------------------------------------------
// GAT pipeline: 3x (GEMM+alpha fused -> CSR segment-softmax aggregate) + FC
// R7: GEMM x-loads back to per-lane broadcast VMEM (R6's scalar path gave
//     VALUBusy 6% -- SMEM pipe serializes). Explicit 2-stage x prefetch.
//     Grid 1280 = 5 blocks/CU (32 KB LDS cap).
// ---------------------------------------------------------------------------

// pass 1: cnt[dst]++ (atomic), remember each edge's arrival rank.
__global__ void count_rank_kernel(const int* __restrict__ ei, int E, int N,
                                  int* __restrict__ cnt, int* __restrict__ rank) {
    const int Etot = E + N;
    const int T = gridDim.x * blockDim.x;
    int e = blockIdx.x * blockDim.x + threadIdx.x;
#pragma unroll 4
    for (int u = 0; u < 4; ++u, e += T) {
        if (e < Etot) {
            int dst = (e < E) ? ei[E + e] : (e - E);   // self-loops appended
            rank[e] = atomicAdd(&cnt[dst], 1);
        }
    }
}

__global__ __launch_bounds__(1024) void scan_kernel(const int* __restrict__ cnt,
                                                    int N, int Etot,
                                                    int* __restrict__ row_ptr) {
    __shared__ int sums[1024];
    int tid = threadIdx.x;
    int chunk = (N + 1023) >> 10;
    int lo = tid * chunk;
    int hi = lo + chunk; if (hi > N) hi = N; if (lo > N) lo = N;
    int s = 0;
    for (int i = lo; i < hi; ++i) s += cnt[i];
    sums[tid] = s;
    __syncthreads();
    for (int off = 1; off < 1024; off <<= 1) {
        int t = (tid >= off) ? sums[tid - off] : 0;
        __syncthreads();
        sums[tid] += t;
        __syncthreads();
    }
    int run = sums[tid] - s;   // exclusive base for this thread's chunk
    for (int i = lo; i < hi; ++i) {
        row_ptr[i] = run;
        run += cnt[i];
    }
    if (tid == 0) row_ptr[N] = Etot;
}

// pass 3: pos = row_ptr[dst] + rank[e]; atomic-free scattered store.
__global__ void scatter_kernel(const int* __restrict__ ei, int E, int N,
                               const int* __restrict__ row_ptr,
                               const int* __restrict__ rank,
                               int* __restrict__ csr_src) {
    const int Etot = E + N;
    const int T = gridDim.x * blockDim.x;
    int e = blockIdx.x * blockDim.x + threadIdx.x;
#pragma unroll 4
    for (int u = 0; u < 4; ++u, e += T) {
        if (e < Etot) {
            int src, dst;
            if (e < E) { src = ei[e]; dst = ei[E + e]; }
            else       { src = e - E; dst = e - E; }
            csr_src[row_ptr[dst] + rank[e]] = src;
        }
    }
}

// ---------------------------------------------------------------------------
// GEMM: out[n, cb+m] = sum_k in[n,k]*W[k,cb+m].  256-thread blocks (4 waves),
// W chunk staged to LDS once (b128 conflict-free), grid-stride over row
// groups of RB=4 rows/wave. x loads are per-lane VMEM reads of a wave-uniform
// address (HW broadcast, one 16B fetch) with explicit next-iter prefetch.
// ALPHA: fused alpha_s/alpha_d via wave shfl reduction over the output row:
//   0=none  1=(H2,C32,PL1: segmented 32-lane)  2=(H2,C64,PL2)  3=(H1,C64,PL1)
// K*CHUNK <= 8192 (32 KB LDS).
// ---------------------------------------------------------------------------
template <int K, int CHUNK, int RB, int ALPHA>
__global__ __launch_bounds__(256) void gemm_kernel(
        const float* __restrict__ in,
        const float* __restrict__ W,
        const float* __restrict__ bias,
        float* __restrict__ out,
        const float* __restrict__ a_src,
        const float* __restrict__ a_dst,
        float* __restrict__ alpS,
        float* __restrict__ alpD,
        int N, int M, int relu) {
    constexpr int PL = CHUNK / 64;
    constexpr int K4 = K / 4;
    __shared__ float wlds[K * CHUNK];
    const int cb = blockIdx.y * CHUNK;
    for (int idx = threadIdx.x; idx < K4 * CHUNK; idx += 256) {
        int k4 = idx / CHUNK, c = idx % CHUNK;
        const float* wp = W + (size_t)(4 * k4) * M + cb + c;
        float4 v;
        v.x = wp[0];
        v.y = wp[(size_t)M];
        v.z = wp[(size_t)2 * M];
        v.w = wp[(size_t)3 * M];
        ((float4*)wlds)[idx] = v;
    }
    __syncthreads();

    const int wid  = threadIdx.x >> 6;
    const int lane = threadIdx.x & 63;
    const float4* wlds4 = (const float4*)wlds;

    float b[PL], aSv[PL], aDv[PL];
#pragma unroll
    for (int j = 0; j < PL; ++j) {
        b[j] = bias ? bias[cb + lane + 64 * j] : 0.0f;
        if (ALPHA) { aSv[j] = a_src[lane + 64 * j]; aDv[j] = a_dst[lane + 64 * j]; }
    }

    const int groups = (N + RB - 1) / RB;
    for (int g = blockIdx.x * 4 + wid; g < groups; g += gridDim.x * 4) {
        const int n0 = g * RB;
        const bool full = (n0 + RB <= N);

        float acc[RB][PL];
#pragma unroll
        for (int r = 0; r < RB; ++r)
#pragma unroll
            for (int j = 0; j < PL; ++j) acc[r][j] = 0.0f;

        const float4* xp = (const float4*)(in + (size_t)n0 * K);

        // 2-stage pipeline: xv = current, prefetch next while FMAing
        float4 xv[RB], xn[RB];
#pragma unroll
        for (int r = 0; r < RB; ++r)
            xv[r] = (full || n0 + r < N) ? xp[(size_t)r * K4]
                                         : make_float4(0.f, 0.f, 0.f, 0.f);

#pragma unroll 2
        for (int k4 = 0; k4 < K4; ++k4) {
            if (k4 + 1 < K4) {
#pragma unroll
                for (int r = 0; r < RB; ++r)
                    xn[r] = (full || n0 + r < N) ? xp[(size_t)r * K4 + k4 + 1]
                                                 : make_float4(0.f, 0.f, 0.f, 0.f);
            }
#pragma unroll
            for (int j = 0; j < PL; ++j) {
                float4 wv = wlds4[k4 * CHUNK + lane + 64 * j];
#pragma unroll
                for (int r = 0; r < RB; ++r) {
                    acc[r][j] += xv[r].x * wv.x;
                    acc[r][j] += xv[r].y * wv.y;
                    acc[r][j] += xv[r].z * wv.z;
                    acc[r][j] += xv[r].w * wv.w;
                }
            }
#pragma unroll
            for (int r = 0; r < RB; ++r) xv[r] = xn[r];
        }

#pragma unroll
        for (int r = 0; r < RB; ++r) {
            if (!full && n0 + r >= N) break;
            const int n = n0 + r;
            float v[PL];
#pragma unroll
            for (int j = 0; j < PL; ++j) {
                v[j] = acc[r][j] + b[j];
                if (relu) v[j] = fmaxf(v[j], 0.0f);
                out[(size_t)n * M + cb + lane + 64 * j] = v[j];
            }
            if (ALPHA) {
                float ps[PL], pd[PL];
#pragma unroll
                for (int j = 0; j < PL; ++j) { ps[j] = v[j] * aSv[j]; pd[j] = v[j] * aDv[j]; }
                const int m0 = (ALPHA == 1) ? 16 : 32;   // 32-lane segmented vs full wave
                for (int m = m0; m >= 1; m >>= 1) {
#pragma unroll
                    for (int j = 0; j < PL; ++j) {
                        ps[j] += __shfl_xor(ps[j], m, 64);
                        pd[j] += __shfl_xor(pd[j], m, 64);
                    }
                }
                if (ALPHA == 1) {
                    if ((lane & 31) == 0) {
                        int idx = n * 2 + (lane >> 5);
                        alpS[idx] = ps[0]; alpD[idx] = pd[0];
                    }
                } else if (ALPHA == 2) {
                    if (lane == 0) {
#pragma unroll
                        for (int j = 0; j < PL; ++j) {
                            alpS[n * 2 + j] = ps[j]; alpD[n * 2 + j] = pd[j];
                        }
                    }
                } else {
                    if (lane == 0) { alpS[n] = ps[0]; alpD[n] = pd[0]; }
                }
            }
        }
    }
}

// ---------------------------------------------------------------------------
// Aggregate: one wave per dst node, single pass, online softmax, 8-edge unroll.
// PL==1: lane -> (head=lane/C, c=lane%C)  [needs H*C==64]
// PL==2: lane covers (head=j, c=lane), j=0,1 [needs C==64,H==2]
// ---------------------------------------------------------------------------
template <int H, int C, int PL>
__global__ __launch_bounds__(256) void aggregate_kernel(
        const float* __restrict__ h,
        const float* __restrict__ alpha_s,
        const float* __restrict__ alpha_d,
        const int* __restrict__ row_ptr,
        const int* __restrict__ csr_src,
        const float* __restrict__ bias,
        float* __restrict__ out, int N) {
    constexpr int M = H * C;
    constexpr int U = 8;
    const int wid  = threadIdx.x >> 6;
    const int lane = threadIdx.x & 63;
    const int n = blockIdx.x * 4 + wid;
    if (n >= N) return;

    const int lo = row_ptr[n], hi = row_ptr[n + 1];

    int head[PL], col[PL];
    float adv[PL], mx[PL], den[PL], acc[PL];
#pragma unroll
    for (int j = 0; j < PL; ++j) {
        head[j] = (PL == 1) ? (lane / C) : j;
        col[j]  = (PL == 1) ? lane : (j * C + lane);
        adv[j]  = alpha_d[n * H + head[j]];
        mx[j]   = -INFINITY;
        den[j]  = 0.0f;
        acc[j]  = 0.0f;
    }

    int e = lo;
    for (; e + U <= hi; e += U) {
        int s[U];
#pragma unroll
        for (int u = 0; u < U; ++u) s[u] = csr_src[e + u];
        float ev[U][PL], hv[U][PL];
#pragma unroll
        for (int u = 0; u < U; ++u)
#pragma unroll
            for (int j = 0; j < PL; ++j)
                ev[u][j] = alpha_s[s[u] * H + head[j]];
#pragma unroll
        for (int u = 0; u < U; ++u)
#pragma unroll
            for (int j = 0; j < PL; ++j)
                hv[u][j] = h[(size_t)s[u] * M + col[j]];
#pragma unroll
        for (int u = 0; u < U; ++u)
#pragma unroll
            for (int j = 0; j < PL; ++j) {
                float evv = ev[u][j] + adv[j];
                evv = evv > 0.0f ? evv : 0.2f * evv;
                float mnew = fmaxf(mx[j], evv);
                float sc = __expf(mx[j] - mnew);   // first edge: exp(-inf)=0
                float p  = __expf(evv - mnew);
                den[j] = den[j] * sc + p;
                acc[j] = acc[j] * sc + p * hv[u][j];
                mx[j]  = mnew;
            }
    }
    for (; e < hi; ++e) {
        int s = csr_src[e];
#pragma unroll
        for (int j = 0; j < PL; ++j) {
            float evv = alpha_s[s * H + head[j]] + adv[j];
            evv = evv > 0.0f ? evv : 0.2f * evv;
            float mnew = fmaxf(mx[j], evv);
            float sc = __expf(mx[j] - mnew);
            float p  = __expf(evv - mnew);
            den[j] = den[j] * sc + p;
            acc[j] = acc[j] * sc + p * h[(size_t)s * M + col[j]];
            mx[j]  = mnew;
        }
    }

#pragma unroll
    for (int j = 0; j < PL; ++j) {
        float v = acc[j] / den[j] + bias[col[j]];
        out[(size_t)n * M + col[j]] = fmaxf(v, 0.0f);
    }
}

// ---------------------------------------------------------------------------

extern "C" void kernel_launch(void* const* d_in, const int* in_sizes, int n_in,
                              void* d_out, int out_size, void* d_ws, size_t ws_size,
                              hipStream_t stream) {
    const float* x   = (const float*)d_in[0];
    const int*   ei  = (const int*)  d_in[1];
    const float* w1  = (const float*)d_in[2];
    const float* as1 = (const float*)d_in[3];
    const float* ad1 = (const float*)d_in[4];
    const float* b1  = (const float*)d_in[5];
    const float* w2  = (const float*)d_in[6];
    const float* as2 = (const float*)d_in[7];
    const float* ad2 = (const float*)d_in[8];
    const float* b2  = (const float*)d_in[9];
    const float* w3  = (const float*)d_in[10];
    const float* as3 = (const float*)d_in[11];
    const float* ad3 = (const float*)d_in[12];
    const float* b3  = (const float*)d_in[13];
    const float* fcw = (const float*)d_in[14];
    const float* fcb = (const float*)d_in[15];
    float* out = (float*)d_out;

    const int N = in_sizes[0] / 128;
    const int E = in_sizes[1] / 2;
    const int Etot = E + N;

    // workspace carve-up (256B aligned regions)
    char* p = (char*)d_ws;
    auto alloc = [&](size_t bytes) {
        char* r = p;
        p += (bytes + 255) & ~(size_t)255;
        return r;
    };
    int*   cnt     = (int*)  alloc((size_t)N * 4);
    int*   row_ptr = (int*)  alloc((size_t)(N + 1) * 4);
    int*   rank    = (int*)  alloc((size_t)Etot * 4);
    int*   csr_src = (int*)  alloc((size_t)Etot * 4);
    float* bufA    = (float*)alloc((size_t)N * 128 * 4);
    float* bufB    = (float*)alloc((size_t)N * 128 * 4);
    float* alpS    = (float*)alloc((size_t)N * 2 * 4);
    float* alpD    = (float*)alloc((size_t)N * 2 * 4);
    (void)ws_size; (void)n_in; (void)out_size;

    // ---- build CSR by dst (atomics only in pass 1) ----
    hipMemsetAsync(cnt, 0, (size_t)N * 4, stream);
    int eb4 = (Etot / 4 + 255) / 256 + 1;   // 4 edges/thread
    count_rank_kernel<<<eb4, 256, 0, stream>>>(ei, E, N, cnt, rank);
    scan_kernel<<<1, 1024, 0, stream>>>(cnt, N, Etot, row_ptr);
    scatter_kernel<<<eb4, 256, 0, stream>>>(ei, E, N, row_ptr, rank, csr_src);

    int gb = (N + 3) / 4;         // aggregate: 4 waves/block, 1 node/wave
    const int GB = 1280;          // gemm persistent blocks: 5/CU (LDS cap)

    // ---- layer 1: 128 -> H2 x C32, concat ----
    gemm_kernel<128, 64, 4, 1><<<dim3(GB, 1), 256, 0, stream>>>(
        x, w1, nullptr, bufA, as1, ad1, alpS, alpD, N, 64, 0);
    aggregate_kernel<2, 32, 1><<<gb, 256, 0, stream>>>(bufA, alpS, alpD, row_ptr, csr_src, b1, bufB, N);

    // ---- layer 2: 64 -> H2 x C64, concat ----
    gemm_kernel<64, 128, 4, 2><<<dim3(GB, 1), 256, 0, stream>>>(
        bufB, w2, nullptr, bufA, as2, ad2, alpS, alpD, N, 128, 0);
    aggregate_kernel<2, 64, 2><<<gb, 256, 0, stream>>>(bufA, alpS, alpD, row_ptr, csr_src, b2, bufB, N);

    // ---- layer 3: 128 -> H1 x C64, mean (=identity for 1 head) ----
    gemm_kernel<128, 64, 4, 3><<<dim3(GB, 1), 256, 0, stream>>>(
        bufB, w3, nullptr, bufA, as3, ad3, alpS, alpD, N, 64, 0);
    aggregate_kernel<1, 64, 1><<<gb, 256, 0, stream>>>(bufA, alpS, alpD, row_ptr, csr_src, b3, bufB, N);

    // ---- FC: 64 -> 512 + relu ----
    gemm_kernel<64, 128, 4, 0><<<dim3(GB / 4, 4), 256, 0, stream>>>(
        bufB, fcw, fcb, out, nullptr, nullptr, nullptr, nullptr, N, 512, 1);
}